// Round 1
// baseline (322.406 us; speedup 1.0000x reference)
//
#include <hip/hip_runtime.h>
#include <math.h>

#define B_  16
#define T_  512
#define S_  1024
#define E_  1024
#define D_  1024

using short8   = __attribute__((ext_vector_type(8))) short;
using ushort4v = __attribute__((ext_vector_type(4))) unsigned short;
using float4v  = __attribute__((ext_vector_type(4))) float;

__device__ __forceinline__ unsigned short f2bf(float f) {
    unsigned u = __builtin_bit_cast(unsigned, f);
    u += 0x7fff + ((u >> 16) & 1);          // round-to-nearest-even
    return (unsigned short)(u >> 16);
}

__device__ __forceinline__ void gl_lds16(const void* g, void* l) {
    __builtin_amdgcn_global_load_lds(
        (const __attribute__((address_space(1))) void*)g,
        (__attribute__((address_space(3))) void*)l, 16, 0, 0);
}

// ---------------------------------------------------------------------------
// Elementwise fp32 -> bf16 cast, 8 elements/thread.
// ---------------------------------------------------------------------------
__global__ __launch_bounds__(256)
void cast_bf16(const float* __restrict__ src, unsigned short* __restrict__ dst, int n8)
{
    int i = blockIdx.x * 256 + threadIdx.x;
    if (i < n8) {
        float4 a = ((const float4*)src)[2 * i];
        float4 b = ((const float4*)src)[2 * i + 1];
        short8 o;
        o[0] = f2bf(a.x); o[1] = f2bf(a.y); o[2] = f2bf(a.z); o[3] = f2bf(a.w);
        o[4] = f2bf(b.x); o[5] = f2bf(b.y); o[6] = f2bf(b.z); o[7] = f2bf(b.w);
        ((short8*)dst)[i] = o;
    }
}

// ---------------------------------------------------------------------------
// Transpose+cast: src (R x C) fp32 row-major -> dst (C x R) bf16 row-major.
// ---------------------------------------------------------------------------
__global__ __launch_bounds__(256)
void transpose_cast(const float* __restrict__ src, unsigned short* __restrict__ dst,
                    int R, int C, long long sSrc, long long sDst)
{
    __shared__ unsigned short tile[64][65];
    const int z = blockIdx.z;
    src += (long long)z * sSrc;
    dst += (long long)z * sDst;
    const int c0 = blockIdx.x * 64;
    const int r0 = blockIdx.y * 64;
    const int t = threadIdx.x;

    #pragma unroll
    for (int it = 0; it < 4; ++it) {
        int r  = (t >> 4) + it * 16;
        int c4 = (t & 15) << 2;
        float4 v = *(const float4*)&src[(long long)(r0 + r) * C + c0 + c4];
        tile[r][c4 + 0] = f2bf(v.x);
        tile[r][c4 + 1] = f2bf(v.y);
        tile[r][c4 + 2] = f2bf(v.z);
        tile[r][c4 + 3] = f2bf(v.w);
    }
    __syncthreads();
    #pragma unroll
    for (int it = 0; it < 2; ++it) {
        int c  = (t >> 3) + it * 32;
        int r8 = (t & 7) << 3;
        short8 sv;
        #pragma unroll
        for (int j = 0; j < 8; ++j) sv[j] = (short)tile[r8 + j][c];
        *(short8*)&dst[(long long)(c0 + c) * R + r0 + r8] = sv;
    }
}

// ---------------------------------------------------------------------------
// Fast MFMA GEMM: C[M,N] = A @ B^T, A (M,K) bf16, B (N,K) bf16, row-major.
// 128x128 tile, BK=64 as TWO stacked [128][32] subtiles (m97-validated lane
// mapping), global_load_lds width-16 staging, ds_read_b128 frags, 16x16x32
// MFMA.  NEW this round: double-buffered LDS + prefetch-before-compute
// (T3 minimum 2-phase recipe).  The STAGE for K-tile k+1 is issued BEFORE
// the ds_read+MFMA of tile k, so the ~160 cycles of MFMA hide the load
// latency instead of exposing it at the barrier; one barrier per K-step
// instead of two.  LDS 64 KiB -> still 2 blocks/CU (grid is 2/CU anyway).
// ---------------------------------------------------------------------------
template<bool OUT_BF16, bool CMASK>
__global__ __launch_bounds__(256, 2)
void mfma_gemm_bf(const unsigned short* __restrict__ Ap,
                  const unsigned short* __restrict__ Bp,
                  const float* __restrict__ mask, void* __restrict__ Cp,
                  int N, int K,
                  long long sA, long long sB, long long sC, int maskStride)
{
    // [buf][subtile j*4096 + it*2048(rows 64..127) interleave]  (ushorts)
    __shared__ unsigned short Asl[2][2 * 128 * 32];
    __shared__ unsigned short Bsl[2][2 * 128 * 32];

    const int z    = blockIdx.z;
    const int col0 = blockIdx.x * 128;
    const int row0 = blockIdx.y * 128;
    const int t    = threadIdx.x;
    const int lane = t & 63;
    const int wave = t >> 6;

    const unsigned short* A  = Ap + z * sA + (long long)row0 * K;
    const unsigned short* Bm = Bp + z * sB + (long long)col0 * K;

    // per-subtile staging: chunk c = it*256 + t covers row = c>>2,
    // k-offset (c&3)*8 of a [128][32] subtile. LDS dest = wave-uniform base
    // (j*8192 + it*4096 + wave*1024 bytes) + lane*16.
    const int rs  = t >> 2;
    const int kcs = (t & 3) << 3;
    const unsigned ldsW = wave * 1024;

    const int wm = (wave >> 1) * 64;
    const int wn = (wave & 1) * 64;
    const int fr = lane & 15;
    const int fg = lane >> 4;

    float4v acc[4][4];
    #pragma unroll
    for (int i = 0; i < 4; ++i)
        #pragma unroll
        for (int j = 0; j < 4; ++j)
            acc[i][j] = (float4v)0.0f;

    // ---- staging helper -------------------------------------------------
    auto STAGE = [&](int bufi, int k0) {
        #pragma unroll
        for (int j = 0; j < 2; ++j) {
            #pragma unroll
            for (int it = 0; it < 2; ++it) {
                const int r = rs + it * 64;
                const long long goff = (long long)r * K + k0 + j * 32 + kcs;
                const unsigned loff = j * 8192 + it * 4096 + ldsW;
                gl_lds16(A  + goff, (char*)&Asl[bufi][0] + loff);
                gl_lds16(Bm + goff, (char*)&Bsl[bufi][0] + loff);
            }
        }
    };

    auto COMPUTE = [&](int bufi) {
        short8 af[2][4], bfr[2][4];
        #pragma unroll
        for (int j = 0; j < 2; ++j) {
            #pragma unroll
            for (int mi = 0; mi < 4; ++mi)
                af[j][mi] = *(const short8*)&Asl[bufi][j * 4096 + (wm + mi * 16 + fr) * 32 + fg * 8];
            #pragma unroll
            for (int ni = 0; ni < 4; ++ni)
                bfr[j][ni] = *(const short8*)&Bsl[bufi][j * 4096 + (wn + ni * 16 + fr) * 32 + fg * 8];
        }
        #pragma unroll
        for (int j = 0; j < 2; ++j)
            #pragma unroll
            for (int mi = 0; mi < 4; ++mi)
                #pragma unroll
                for (int ni = 0; ni < 4; ++ni)
                    acc[mi][ni] = __builtin_amdgcn_mfma_f32_16x16x32_bf16(af[j][mi], bfr[j][ni], acc[mi][ni], 0, 0, 0);
    };

    // ---- prologue: fill buffer 0 ---------------------------------------
    STAGE(0, 0);
    __syncthreads();              // includes vmcnt(0) drain of the stage

    int buf = 0;
    for (int k0 = 64; k0 <= K; k0 += 64) {
        if (k0 < K) STAGE(buf ^ 1, k0);   // prefetch next tile BEFORE compute
        COMPUTE(buf);
        // ds_reads of buf retired before each wave's MFMAs (lgkmcnt), MFMAs
        // precede the barrier; barrier's vmcnt(0) finishes the prefetch.
        __syncthreads();
        buf ^= 1;
    }

    float mv[4];
    #pragma unroll
    for (int ni = 0; ni < 4; ++ni) {
        int ocol = col0 + wn + ni * 16 + fr;
        mv[ni] = CMASK ? mask[(long long)z * maskStride + ocol] : 1.0f;
    }
    #pragma unroll
    for (int mi = 0; mi < 4; ++mi) {
        #pragma unroll
        for (int ni = 0; ni < 4; ++ni) {
            int ocol = col0 + wn + ni * 16 + fr;
            #pragma unroll
            for (int r = 0; r < 4; ++r) {
                int orow = row0 + wm + mi * 16 + fg * 4 + r;
                float v = acc[mi][ni][r] * mv[ni];
                if (OUT_BF16)
                    ((unsigned short*)Cp)[z * sC + (long long)orow * N + ocol] = f2bf(v);
                else
                    ((float*)Cp)[z * sC + (long long)orow * N + ocol] = v;
            }
        }
    }
}

// ---------------------------------------------------------------------------
// Masked softmax; also writes a bf16 copy of the weights when wbf != nullptr.
// ---------------------------------------------------------------------------
__global__ __launch_bounds__(256)
void softmax_mask(const float* __restrict__ x, const float* __restrict__ mask,
                  float* __restrict__ w, unsigned short* __restrict__ wbf)
{
    const int row = blockIdx.x;
    const int b   = row >> 9;             // T_=512
    const float* xr = x    + (long long)row * S_;
    const float* mr = mask + (long long)b * S_;
    float*       wr = w    + (long long)row * S_;
    const int tid = threadIdx.x;

    float4 xv = ((const float4*)xr)[tid];
    float4 mv = ((const float4*)mr)[tid];

    float lmax = fmaxf(fmaxf(xv.x, xv.y), fmaxf(xv.z, xv.w));
    #pragma unroll
    for (int off = 32; off; off >>= 1)
        lmax = fmaxf(lmax, __shfl_xor(lmax, off, 64));

    __shared__ float red[4];
    const int wave = tid >> 6, lane = tid & 63;
    if (lane == 0) red[wave] = lmax;
    __syncthreads();
    const float rmax = fmaxf(fmaxf(red[0], red[1]), fmaxf(red[2], red[3]));

    float e0 = expf(xv.x - rmax) * mv.x;
    float e1 = expf(xv.y - rmax) * mv.y;
    float e2 = expf(xv.z - rmax) * mv.z;
    float e3 = expf(xv.w - rmax) * mv.w;

    float lsum = (e0 + e1) + (e2 + e3);
    #pragma unroll
    for (int off = 32; off; off >>= 1)
        lsum += __shfl_xor(lsum, off, 64);

    __syncthreads();
    if (lane == 0) red[wave] = lsum;
    __syncthreads();
    const float rsum = (red[0] + red[1]) + (red[2] + red[3]);
    const float inv = 1.0f / (rsum + 1e-6f);

    float4 o;
    o.x = e0 * inv; o.y = e1 * inv; o.z = e2 * inv; o.w = e3 * inv;
    ((float4*)wr)[tid] = o;
    if (wbf) {
        ushort4v u;
        u[0] = f2bf(o.x); u[1] = f2bf(o.y); u[2] = f2bf(o.z); u[3] = f2bf(o.w);
        ((ushort4v*)(wbf + (long long)row * S_))[tid] = u;
    }
}

// ---------------------------------------------------------------------------
// fp32 fallback GEMM (round-1 validated) — used only if d_ws is tiny.
// ---------------------------------------------------------------------------
constexpr int FBM = 64, FBN = 64, FBK = 16;
template<bool BT, bool CMASK>
__global__ __launch_bounds__(256)
void gemm_f32(const float* __restrict__ A, const float* __restrict__ Bm,
              const float* __restrict__ mask, float* __restrict__ C,
              int N_dim, int K_dim,
              long long sA, long long sB, long long sC, int maskStride)
{
    const int bz = blockIdx.z;
    A  += (long long)bz * sA;
    Bm += (long long)bz * sB;
    C  += (long long)bz * sC;
    __shared__ float As[FBK][FBM];
    __shared__ float Bs[FBK][FBN];
    const int tid  = threadIdx.x;
    const int row0 = blockIdx.y * FBM;
    const int col0 = blockIdx.x * FBN;
    const int lrow = tid >> 2;
    const int lk   = (tid & 3) << 2;
    const int bk = tid >> 4;
    const int bn = (tid & 15) << 2;
    const int tx = tid & 15;
    const int ty = tid >> 4;
    float acc[4][4] = {};
    const float* Aptr = A + (long long)(row0 + lrow) * K_dim + lk;
    const float* Bptr = BT ? (Bm + (long long)(col0 + lrow) * K_dim + lk)
                           : (Bm + (long long)bk * N_dim + col0 + bn);
    for (int k0 = 0; k0 < K_dim; k0 += FBK) {
        float4 av = *(const float4*)(Aptr + k0);
        As[lk + 0][lrow] = av.x; As[lk + 1][lrow] = av.y;
        As[lk + 2][lrow] = av.z; As[lk + 3][lrow] = av.w;
        if (BT) {
            float4 bv = *(const float4*)(Bptr + k0);
            Bs[lk + 0][lrow] = bv.x; Bs[lk + 1][lrow] = bv.y;
            Bs[lk + 2][lrow] = bv.z; Bs[lk + 3][lrow] = bv.w;
        } else {
            float4 bv = *(const float4*)(Bptr + (long long)k0 * N_dim);
            *(float4*)&Bs[bk][bn] = bv;
        }
        __syncthreads();
        #pragma unroll
        for (int k = 0; k < FBK; ++k) {
            float4 a4 = *(const float4*)&As[k][ty << 2];
            float4 b4 = *(const float4*)&Bs[k][tx << 2];
            float ar[4] = {a4.x, a4.y, a4.z, a4.w};
            float br[4] = {b4.x, b4.y, b4.z, b4.w};
            #pragma unroll
            for (int i = 0; i < 4; ++i)
                #pragma unroll
                for (int j = 0; j < 4; ++j)
                    acc[i][j] = fmaf(ar[i], br[j], acc[i][j]);
        }
        __syncthreads();
    }
    float mvv[4] = {1.f, 1.f, 1.f, 1.f};
    if (CMASK) {
        #pragma unroll
        for (int j = 0; j < 4; ++j)
            mvv[j] = mask[(long long)bz * maskStride + col0 + (tx << 2) + j];
    }
    #pragma unroll
    for (int i = 0; i < 4; ++i) {
        const int r = row0 + (ty << 2) + i;
        float4 o;
        o.x = acc[i][0] * mvv[0]; o.y = acc[i][1] * mvv[1];
        o.z = acc[i][2] * mvv[2]; o.w = acc[i][3] * mvv[3];
        *(float4*)&C[(long long)r * N_dim + col0 + (tx << 2)] = o;
    }
}

extern "C" void kernel_launch(void* const* d_in, const int* in_sizes, int n_in,
                              void* d_out, int out_size, void* d_ws, size_t ws_size,
                              hipStream_t stream)
{
    const float* hidden = (const float*)d_in[0];   // (B,T,D)
    const float* eo     = (const float*)d_in[1];   // (B,S,E)
    const float* ev     = (const float*)d_in[2];   // (B,S,D)
    const float* mask   = (const float*)d_in[3];   // (B,S)
    const float* W      = (const float*)d_in[4];   // (D,E)

    float* out = (float*)d_out;
    const long long CTX = (long long)B_ * T_ * D_;
    float* ctx = out;
    float* aw  = out + CTX;
    float* ae  = out + 2 * CTX;

    dim3 blk(256);
    const size_t MB = 1024ull * 1024ull;
    const size_t NEED_FAST = 64 * MB;

    if (ws_size >= NEED_FAST) {
        // Phased workspace layout (aliasing by live range):
        //   [0,16)  Hbf  (dead after K1) -> EObf [0,32) after K1
        //   [16,18) WT   (dead after K1)
        //   [16,48) EVT  (written after K2)
        //   [48,64) G    (dead after K2) -> AWbf
        char* ws = (char*)d_ws;
        unsigned short* Hbf  = (unsigned short*)(ws);
        unsigned short* WT   = (unsigned short*)(ws + 16 * MB);
        unsigned short* EObf = (unsigned short*)(ws);
        unsigned short* EVT  = (unsigned short*)(ws + 16 * MB);
        unsigned short* G    = (unsigned short*)(ws + 48 * MB);
        unsigned short* AWbf = (unsigned short*)(ws + 48 * MB);

        cast_bf16<<<dim3((B_ * T_ * D_ / 8 + 255) / 256), blk, 0, stream>>>(
            hidden, Hbf, B_ * T_ * D_ / 8);
        transpose_cast<<<dim3(E_ / 64, D_ / 64, 1), blk, 0, stream>>>(
            W, WT, D_, E_, 0, 0);

        // K1: G = Hbf @ WT^T  -> bf16
        mfma_gemm_bf<true, false><<<dim3(E_ / 128, (B_ * T_) / 128, 1), blk, 0, stream>>>(
            Hbf, WT, nullptr, G, E_, D_, 0, 0, 0, 0);

        cast_bf16<<<dim3((B_ * S_ * E_ / 8 + 255) / 256), blk, 0, stream>>>(
            eo, EObf, B_ * S_ * E_ / 8);

        // K2: ae[b,t,s] = mask[b,s] * (G[b,t,:] . EObf[b,s,:])
        mfma_gemm_bf<false, true><<<dim3(S_ / 128, T_ / 128, B_), blk, 0, stream>>>(
            G, EObf, mask, ae, S_, E_,
            (long long)T_ * E_, (long long)S_ * E_, (long long)T_ * S_, S_);

        // EVt[b][d][s] = EV[b][s][d]
        transpose_cast<<<dim3(D_ / 64, S_ / 64, B_), blk, 0, stream>>>(
            ev, EVT, S_, D_, (long long)S_ * D_, (long long)D_ * S_);

        // K3: softmax -> aw (fp32) + AWbf (bf16, aliases G)
        softmax_mask<<<dim3(B_ * T_), blk, 0, stream>>>(ae, mask, aw, AWbf);

        // K4: ctx = AWbf @ EVT^T
        mfma_gemm_bf<false, false><<<dim3(D_ / 128, T_ / 128, B_), blk, 0, stream>>>(
            AWbf, EVT, nullptr, ctx, D_, S_,
            (long long)T_ * S_, (long long)D_ * S_, (long long)T_ * D_, 0);
    } else {
        float* G = aw;
        gemm_f32<false, false><<<dim3(E_ / FBN, (B_ * T_) / FBM, 1), blk, 0, stream>>>(
            hidden, W, nullptr, G, E_, D_, 0, 0, 0, 0);
        gemm_f32<true, true><<<dim3(S_ / FBN, T_ / FBM, B_), blk, 0, stream>>>(
            G, eo, mask, ae, S_, E_,
            (long long)T_ * E_, (long long)S_ * E_, (long long)T_ * S_, S_);
        softmax_mask<<<dim3(B_ * T_), blk, 0, stream>>>(ae, mask, aw, nullptr);
        gemm_f32<false, false><<<dim3(D_ / FBN, T_ / FBM, B_), blk, 0, stream>>>(
            aw, ev, nullptr, ctx, D_, S_,
            (long long)T_ * S_, (long long)S_ * D_, (long long)T_ * D_, 0);
    }
}